// Round 1
// baseline (346.340 us; speedup 1.0000x reference)
//
#include <hip/hip_runtime.h>

// Butterfly multiply, n=1024, log_n=10, nstacks=nblocks=1, increasing stride.
// x: (32768, 1024) f32; twiddle: (10, 512, 2, 2) f32; bias: (1024,) f32.
//
// Mapping: one wave (64 lanes) processes ROWS_PER_WAVE rows. Lane l holds
// elements [l*16, l*16+16) of each row in registers.
//   stages 0..3 (stride 1..8):  within-lane register butterflies
//   stages 4..9 (stride 16..512): __shfl_xor with mask 1<<(stage-4)
// Twiddle for stage s, position p: pair = p with bit s deleted,
// 2x2 at tw[s*2048 + pair*4]. For cross-lane stages a lane only needs its
// own output row of the 2x2; the o0/o1 swap is folded into the load.

#define ROWS_PER_WAVE 4
#define N 1024

__global__ __launch_bounds__(256, 4) void butterfly_kernel(
    const float* __restrict__ x,
    const float* __restrict__ tw,
    const float* __restrict__ bias,
    float* __restrict__ out,
    int nRows)
{
    const int lane = threadIdx.x & 63;
    const int waveInBlock = threadIdx.x >> 6;
    const int waveId = blockIdx.x * 4 + waveInBlock;
    const long rowBase = (long)waveId * ROWS_PER_WAVE;
    if (rowBase >= nRows) return;

    const int off = lane * 16;

    float v[ROWS_PER_WAVE][16];

    // ---- load rows (coalesced: wave covers 1024 consecutive floats) ----
    #pragma unroll
    for (int r = 0; r < ROWS_PER_WAVE; ++r) {
        const float4* p = (const float4*)(x + (rowBase + r) * N + off);
        #pragma unroll
        for (int q = 0; q < 4; ++q) {
            float4 f = p[q];
            v[r][q*4+0] = f.x; v[r][q*4+1] = f.y;
            v[r][q*4+2] = f.z; v[r][q*4+3] = f.w;
        }
    }

    // ---- stages 0..3: within-lane (stride 1,2,4,8) ----
    #pragma unroll
    for (int stage = 0; stage < 4; ++stage) {
        const int s = 1 << stage;
        // lane's 8 pairs are twiddle indices [lane*8, lane*8+8) -> 32 consec floats
        float t[32];
        const float4* tp = (const float4*)(tw + stage * 2048 + lane * 32);
        #pragma unroll
        for (int q = 0; q < 8; ++q) {
            float4 f = tp[q];
            t[q*4+0] = f.x; t[q*4+1] = f.y; t[q*4+2] = f.z; t[q*4+3] = f.w;
        }
        #pragma unroll
        for (int r = 0; r < ROWS_PER_WAVE; ++r) {
            #pragma unroll
            for (int j = 0; j < 8; ++j) {
                const int p0 = ((j >> stage) << (stage + 1)) | (j & (s - 1));
                const int p1 = p0 | s;
                float a = v[r][p0], b = v[r][p1];
                v[r][p0] = t[j*4+0] * a + t[j*4+1] * b;
                v[r][p1] = t[j*4+2] * a + t[j*4+3] * b;
            }
        }
    }

    // ---- stages 4..9: cross-lane (stride 16..512) ----
    #pragma unroll
    for (int stage = 4; stage < 10; ++stage) {
        const int lm = stage - 4;
        const int m = 1 << lm;
        const int i = (lane >> lm) & 1;                        // my row of the 2x2
        const int pl = ((lane >> (lm + 1)) << lm) | (lane & (m - 1)); // lane w/ bit lm deleted
        // my 16 pairs are twiddle indices [pl*16, pl*16+16)
        const float* tb = tw + stage * 2048 + pl * 64 + i * 2;
        float ta_[16], tb_[16];   // coeff of (mine, other) — swap folded in here
        #pragma unroll
        for (int k = 0; k < 16; ++k) {
            float2 raw = *(const float2*)(tb + k * 4);   // (t[i][0], t[i][1])
            ta_[k] = i ? raw.y : raw.x;   // coeff of my element  (o_i)
            tb_[k] = i ? raw.x : raw.y;   // coeff of partner     (o_{1-i})
        }
        #pragma unroll
        for (int r = 0; r < ROWS_PER_WAVE; ++r) {
            #pragma unroll
            for (int k = 0; k < 16; ++k) {
                float mine  = v[r][k];
                float other = __shfl_xor(mine, m, 64);
                v[r][k] = ta_[k] * mine + tb_[k] * other;
            }
        }
    }

    // ---- bias + store ----
    float bv[16];
    {
        const float4* bp = (const float4*)(bias + off);
        #pragma unroll
        for (int q = 0; q < 4; ++q) {
            float4 f = bp[q];
            bv[q*4+0] = f.x; bv[q*4+1] = f.y; bv[q*4+2] = f.z; bv[q*4+3] = f.w;
        }
    }
    #pragma unroll
    for (int r = 0; r < ROWS_PER_WAVE; ++r) {
        float4* p = (float4*)(out + (rowBase + r) * N + off);
        #pragma unroll
        for (int q = 0; q < 4; ++q) {
            float4 f;
            f.x = v[r][q*4+0] + bv[q*4+0];
            f.y = v[r][q*4+1] + bv[q*4+1];
            f.z = v[r][q*4+2] + bv[q*4+2];
            f.w = v[r][q*4+3] + bv[q*4+3];
            p[q] = f;
        }
    }
}

extern "C" void kernel_launch(void* const* d_in, const int* in_sizes, int n_in,
                              void* d_out, int out_size, void* d_ws, size_t ws_size,
                              hipStream_t stream) {
    const float* x    = (const float*)d_in[0];
    const float* tw   = (const float*)d_in[1];
    const float* bias = (const float*)d_in[2];
    float* out = (float*)d_out;

    const int nRows = in_sizes[0] / N;                       // 32768
    const int waves = (nRows + ROWS_PER_WAVE - 1) / ROWS_PER_WAVE;
    const int blocks = (waves + 3) / 4;                      // 4 waves / block

    butterfly_kernel<<<blocks, 256, 0, stream>>>(x, tw, bias, out, nRows);
}